// Round 2
// baseline (794.571 us; speedup 1.0000x reference)
//
#include <hip/hip_runtime.h>

#define DEV __device__ __forceinline__

typedef __bf16 bf16x8 __attribute__((ext_vector_type(8)));
typedef float f32x4 __attribute__((ext_vector_type(4)));
typedef unsigned int u32;

constexpr int BROWS = 8192;
constexpr int D = 1024;
constexpr int SD = 4096;

// ---------------- helpers ----------------
DEV unsigned short f2bf(float f) {  // RNE float->bf16
  unsigned int u = __float_as_uint(f);
  u = (u + 0x7FFFu + ((u >> 16) & 1u)) >> 16;
  return (unsigned short)u;
}

DEV float wred(float v) {  // full 64-lane butterfly sum (result in all lanes)
#pragma unroll
  for (int m = 1; m < 64; m <<= 1) v += __shfl_xor(v, m);
  return v;
}

DEV float sigmoidf(float x) { return 1.0f / (1.0f + __expf(-x)); }

DEV void async_ld16(const void* g, void* l) {  // 16B global -> LDS DMA
  __builtin_amdgcn_global_load_lds((const __attribute__((address_space(1))) u32*)g,
                                   (__attribute__((address_space(3))) u32*)l, 16, 0, 0);
}

// ---------------- K0: prep — W_layer->bf16, pack 24 gate rows, row-sums ----
__global__ __launch_bounds__(256) void k0_prep(
    const float* __restrict__ Wlayer, const float* __restrict__ Wpre,
    const float* __restrict__ Wpost, const float* __restrict__ Wres,
    unsigned short* __restrict__ wl16, float* __restrict__ Wall,
    float* __restrict__ wsum) {
  const int bx = blockIdx.x, tid = threadIdx.x;
  if (bx < 1024) {  // W_layer fp32 -> bf16
    const int i = bx * 1024 + tid * 4;
    float4 v = *(const float4*)(Wlayer + i);
    ushort4 u = make_ushort4(f2bf(v.x), f2bf(v.y), f2bf(v.z), f2bf(v.w));
    *(ushort4*)(wl16 + i) = u;
  } else {  // pack gate row j into Wall + row-sum
    const int j = bx - 1024;  // 0..23
    const float* src = (j < 4) ? (Wpre + j * SD)
                               : (j < 8 ? (Wpost + (j - 4) * SD) : (Wres + (j - 8) * SD));
    float s = 0.f;
    for (int i = tid * 4; i < SD; i += 1024) {
      float4 v = *(const float4*)(src + i);
      *(float4*)(Wall + j * SD + i) = v;
      s += v.x + v.y + v.z + v.w;
    }
    s = wred(s);
    __shared__ float tmp[4];
    if ((tid & 63) == 0) tmp[tid >> 6] = s;
    __syncthreads();
    if (tid == 0) wsum[j] = tmp[0] + tmp[1] + tmp[2] + tmp[3];
  }
}

// ---------------- K1: fused per-row pass, LDS-staged pipelined ----------------
// Block = 8 rows, 8 waves (512 thr). x DMA'd (global_load_lds) into a 4-slot
// LDS ring; ALL waves read x from LDS. Wave w: dots j in [3w,3w+3) for all 8
// rows (acc[3][8]=24 regs) + stats for row w only (2 regs). W double-buffered
// in regs (2x3 float4 = 24 regs) from L2-hot Wall. Per-wave live set ~100 regs
// -> fits 128-cap (launch_bounds 512,4 = 2 blocks/CU), NO scratch (round-1's
// 536MB WRITE_SIZE was xv[8]+wbuf spill at 84 allocated regs).
// Sync per K-step: counted s_waitcnt vmcnt(N) + raw s_barrier, never vmcnt(0).
// FIFO per iter i: issue W(i+1) x3, DMA(i+2) x1 -> newer-than-DMA(i) = 8.
// Prologue fenced so counts are exact: iter0=8, steady=8, iter14=7, iter15=3.
// lgkmcnt(0) before each barrier drains ds_reads -> WAR on ring slots closed
// (slot reused after 4 steps >> 1 barrier of wave skew).
__global__ __launch_bounds__(512, 4) void k1_rowpass(
    const float* __restrict__ xs, const float* __restrict__ Wall,
    const float* __restrict__ bpre, const float* __restrict__ bpost,
    const float* __restrict__ bres,
    const float* __restrict__ s_apre, const float* __restrict__ s_apost,
    const float* __restrict__ s_ares,
    const float* __restrict__ gamma, const float* __restrict__ beta,
    const float* __restrict__ wsum,
    unsigned short* __restrict__ lnagg,
    float* __restrict__ hres_g, float* __restrict__ hpost_g) {
  const int tid = threadIdx.x;
  const int wv = tid >> 6;   // 0..7
  const int ln = tid & 63;
  const int rb = blockIdx.x * 8;
  const int l4 = ln * 4;

  __shared__ float XR[4][8][256];  // 32 KB x ring: [slot][row][k-chunk]
  __shared__ float DOT[24][8];
  __shared__ float MU[8];
  __shared__ float RSH[8];
  __shared__ float HPRE[8][4];
  float* XR0 = &XR[0][0][0];

  const int jb = wv * 3;
  const float* Wb = Wall + (size_t)jb * SD;
  // DMA: wave w stages row w. LDS dest = slot base + tid*16B -> row tid>>6=wv,
  // col (tid&63)*4 = l4 — matches the contiguity contract of global_load_lds.
  const float* gx = xs + (size_t)(rb + wv) * SD + l4;

  float acc[3][8];
#pragma unroll
  for (int q = 0; q < 3; ++q)
#pragma unroll
    for (int r = 0; r < 8; ++r) acc[q][r] = 0.f;
  float s2 = 0.f, q2 = 0.f;  // stats for row wv

  float4 wbufA[3], wbufB[3];

#define LDW(dst, it)                                                      \
  {                                                                       \
    const float* p_ = Wb + (it) * 256 + l4;                               \
    _Pragma("unroll") for (int q = 0; q < 3; ++q) dst[q] =                \
        *(const float4*)(p_ + (size_t)q * SD);                            \
  }
#define DMA1(it)                                                          \
  async_ld16(gx + (it) * 256, XR0 + ((it) & 3) * 2048 + tid * 4);
#define CMP(it, W)                                                        \
  {                                                                       \
    const int so_ = ((it) & 3) * 2048;                                    \
    float4 sv_ = *(const float4*)(XR0 + so_ + wv * 256 + l4);             \
    s2 += sv_.x + sv_.y + sv_.z + sv_.w;                                  \
    q2 += sv_.x * sv_.x + sv_.y * sv_.y + sv_.z * sv_.z + sv_.w * sv_.w;  \
    _Pragma("unroll") for (int r = 0; r < 8; ++r) {                       \
      float4 xv_ = *(const float4*)(XR0 + so_ + r * 256 + l4);            \
      _Pragma("unroll") for (int q = 0; q < 3; ++q) acc[q][r] +=          \
          W[q].x * xv_.x + W[q].y * xv_.y + W[q].z * xv_.z +              \
          W[q].w * xv_.w;                                                 \
    }                                                                     \
  }
#define KSTEP(I, WCUR, WNXT, LIT, DOW, DODMA)                             \
  {                                                                       \
    if (DOW) LDW(WNXT, (I) + 1);                                          \
    if (DODMA) DMA1((I) + 2);                                             \
    asm volatile("s_waitcnt vmcnt(" LIT ") lgkmcnt(0)" ::: "memory");     \
    __builtin_amdgcn_s_barrier();                                         \
    asm volatile("" ::: "memory");                                        \
    CMP(I, WCUR);                                                         \
  }

  // prologue (fenced so the vmcnt FIFO counts are exact)
  DMA1(0);
  DMA1(1);
  asm volatile("" ::: "memory");
  LDW(wbufA, 0);

  KSTEP(0, wbufA, wbufB, "8", 1, 1)
#pragma unroll
  for (int i = 1; i <= 11; i += 2) {
    KSTEP(i, wbufB, wbufA, "8", 1, 1)
    KSTEP(i + 1, wbufA, wbufB, "8", 1, 1)
  }
  KSTEP(13, wbufB, wbufA, "8", 1, 1)
  KSTEP(14, wbufA, wbufB, "7", 1, 0)
  KSTEP(15, wbufB, wbufA, "3", 0, 0)
#undef KSTEP
#undef CMP
#undef DMA1
#undef LDW

  // ---- reductions (butterfly; result in all lanes) ----
#pragma unroll
  for (int q = 0; q < 3; ++q)
#pragma unroll
    for (int r = 0; r < 8; ++r) acc[q][r] = wred(acc[q][r]);
  s2 = wred(s2);
  q2 = wred(q2);

  if (ln == 0) {
#pragma unroll
    for (int q = 0; q < 3; ++q)
#pragma unroll
      for (int r = 0; r < 8; ++r) DOT[jb + q][r] = acc[q][r];
    const float mu = s2 * (1.0f / 4096.0f);
    MU[wv] = mu;
    RSH[wv] = rsqrtf(q2 * (1.0f / 4096.0f) - mu * mu + 1e-5f);
  }
  __syncthreads();

  // ---- gates ----
  if (wv < 2) {  // sinkhorn: wave w -> rows 4w..4w+3; 64 lanes = 4 rows x 16
    const float ares = s_ares[0];
    const int rr = (wv << 2) + (ln >> 4), jj = ln & 15;
    const float corr = RSH[rr] * (DOT[8 + jj][rr] - MU[rr] * wsum[8 + jj]);
    float M = __expf(ares * (corr + bres[jj]));
#pragma unroll 1
    for (int itr = 0; itr < 20; ++itr) {
      float rs_ = M + __shfl_xor(M, 1);
      rs_ += __shfl_xor(rs_, 2);
      M *= __builtin_amdgcn_rcpf(rs_ + 1e-8f);
      float cs = M + __shfl_xor(M, 4);
      cs += __shfl_xor(cs, 8);
      M *= __builtin_amdgcn_rcpf(cs + 1e-8f);
    }
    hres_g[(size_t)(rb + rr) * 16 + jj] = M;
  } else if (wv == 2) {
    if (ln < 32) {
      const int r = ln >> 2, s = ln & 3;
      const float corr = RSH[r] * (DOT[s][r] - MU[r] * wsum[s]);
      HPRE[r][s] = sigmoidf(s_apre[0] * (corr + bpre[s]));
    }
  } else if (wv == 3) {
    if (ln < 32) {
      const int r = ln >> 2, s = ln & 3;
      const float corr = RSH[r] * (DOT[4 + s][r] - MU[r] * wsum[4 + s]);
      hpost_g[(size_t)(rb + r) * 4 + s] = 2.0f * sigmoidf(s_apost[0] * (corr + bpost[s]));
    }
  }
  __syncthreads();

  // ---- phase 2: x_agg + LN + bf16 store — wave w owns row rb+w
  // (x re-read hits L2/L3: FETCH_SIZE confirms ~1x x total)
  {
    const int b = rb + wv;
    const float* xb = xs + (size_t)b * SD;
    const float h0 = HPRE[wv][0], h1 = HPRE[wv][1], h2 = HPRE[wv][2], h3 = HPRE[wv][3];
    float4 agg[4];
    float asum = 0.f, asq = 0.f;
#pragma unroll
    for (int i2 = 0; i2 < 4; ++i2) {
      const int d = i2 * 256 + l4;
      float4 g0 = *(const float4*)(xb + d);
      float4 g1 = *(const float4*)(xb + D + d);
      float4 g2 = *(const float4*)(xb + 2 * D + d);
      float4 g3 = *(const float4*)(xb + 3 * D + d);
      float4 a;
      a.x = h0 * g0.x + h1 * g1.x + h2 * g2.x + h3 * g3.x;
      a.y = h0 * g0.y + h1 * g1.y + h2 * g2.y + h3 * g3.y;
      a.z = h0 * g0.z + h1 * g1.z + h2 * g2.z + h3 * g3.z;
      a.w = h0 * g0.w + h1 * g1.w + h2 * g2.w + h3 * g3.w;
      agg[i2] = a;
      asum += a.x + a.y + a.z + a.w;
      asq += a.x * a.x + a.y * a.y + a.z * a.z + a.w * a.w;
    }
    asum = wred(asum);
    asq = wred(asq);
    const float mu2 = asum * (1.0f / 1024.0f);
    const float rstd2 = rsqrtf(asq * (1.0f / 1024.0f) - mu2 * mu2 + 1e-5f);
#pragma unroll
    for (int i2 = 0; i2 < 4; ++i2) {
      const int d = i2 * 256 + l4;
      float4 g = *(const float4*)(gamma + d);
      float4 bb = *(const float4*)(beta + d);
      ushort4 u;
      u.x = f2bf((agg[i2].x - mu2) * rstd2 * g.x + bb.x);
      u.y = f2bf((agg[i2].y - mu2) * rstd2 * g.y + bb.y);
      u.z = f2bf((agg[i2].z - mu2) * rstd2 * g.z + bb.z);
      u.w = f2bf((agg[i2].w - mu2) * rstd2 * g.w + bb.w);
      *(ushort4*)(lnagg + (size_t)b * D + d) = u;
    }
  }
}

// ---------------- K2: bf16 MFMA GEMM + fused epilogue ----------------
__global__ __launch_bounds__(256) void k2_gemm_ep(
    const unsigned short* __restrict__ A,   // lnagg bf16 [8192][1024]
    const unsigned short* __restrict__ Bw,  // W_layer bf16 [1024][1024]
    const float* __restrict__ blayer,
    const float* __restrict__ xs,
    const float* __restrict__ hres_g, const float* __restrict__ hpost_g,
    float* __restrict__ outMean, float* __restrict__ outUpd) {
  __shared__ char smem[44032];
  char* AsB = smem;            // 16384 B: 128 rows x 64 bf16 (8 chunks of 16B)
  char* BsB = smem + 16384;    // 16384 B
  float* EP = (float*)smem;    // epilogue overlay: 32 x 132 fp32 = 16896 B
  float* HR = (float*)(smem + 32768);  // 128 x 17
  float* HP = (float*)(smem + 41472);  // 128 x 5

  const int tid = threadIdx.x;
  const int l = tid & 63;
  const int wv = tid >> 6;
  const int wm = wv >> 1, wn = wv & 1;
  const int lrow = l & 15, lq = l >> 4;
  const int bm0 = blockIdx.x * 128;
  const int bn0 = blockIdx.y * 128;

#pragma unroll
  for (int i = 0; i < 8; ++i) {
    int idx = i * 256 + tid;  // 0..2047
    HR[(idx >> 4) * 17 + (idx & 15)] = hres_g[(size_t)bm0 * 16 + idx];
  }
#pragma unroll
  for (int i = 0; i < 2; ++i) {
    int idx = i * 256 + tid;  // 0..511
    HP[(idx >> 2) * 5 + (idx & 3)] = hpost_g[(size_t)bm0 * 4 + idx];
  }

  f32x4 acc[4][4] = {};

#pragma unroll 1
  for (int kt = 0; kt < 16; ++kt) {
    __syncthreads();
#pragma unroll
    for (int c = 0; c < 4; ++c) {
      const int idx = c * 256 + tid;              // 16B-chunk index 0..1023
      const int row = idx >> 3, cc = idx & 7;
      const int gch = cc ^ (row & 7);             // XOR swizzle on global side
      async_ld16((const char*)A + ((size_t)(bm0 + row) << 11) + kt * 128 + gch * 16,
                 AsB + idx * 16);
      async_ld16((const char*)Bw + ((size_t)(bn0 + row) << 11) + kt * 128 + gch * 16,
                 BsB + idx * 16);
    }
    __syncthreads();
#pragma unroll
    for (int kk = 0; kk < 2; ++kk) {
      bf16x8 af[4], bfr[4];
      const int sw = (kk * 4 + lq);
#pragma unroll
      for (int t = 0; t < 4; ++t) {
        const int ra = wm * 64 + t * 16 + lrow;
        const int rbr = wn * 64 + t * 16 + lrow;
        af[t] = *(const bf16x8*)(AsB + ra * 128 + (sw ^ (ra & 7)) * 16);
        bfr[t] = *(const bf16x8*)(BsB + rbr * 128 + (sw ^ (rbr & 7)) * 16);
      }
#pragma unroll
      for (int ti = 0; ti < 4; ++ti)
#pragma unroll
        for (int tj = 0; tj < 4; ++tj)
          acc[ti][tj] =
              __builtin_amdgcn_mfma_f32_16x16x32_bf16(af[ti], bfr[tj], acc[ti][tj], 0, 0, 0);
    }
  }

  // ---- epilogue: 4 chunks of 32 rows; LDS transpose then nt-vector stream
#pragma unroll
  for (int ti = 0; ti < 4; ++ti) {
    __syncthreads();
#pragma unroll
    for (int tj = 0; tj < 4; ++tj)
#pragma unroll
      for (int r2 = 0; r2 < 4; ++r2)
        EP[(wm * 16 + lq * 4 + r2) * 132 + wn * 64 + tj * 16 + lrow] = acc[ti][tj][r2];
    __syncthreads();

    const int rr2 = tid >> 3;        // 0..31
    const int c0 = (tid & 7) * 4;    // first float4 col, stride 32 over k2i
    const int bl = (rr2 >> 4) * 64 + ti * 16 + (rr2 & 15);
    const int gr = bm0 + bl;
    float hr[16], hp4[4];
#pragma unroll
    for (int q = 0; q < 16; ++q) hr[q] = HR[bl * 17 + q];
#pragma unroll
    for (int q = 0; q < 4; ++q) hp4[q] = HP[bl * 5 + q];
    const float cm0 = 0.25f * (hr[0] + hr[4] + hr[8] + hr[12]);
    const float cm1 = 0.25f * (hr[1] + hr[5] + hr[9] + hr[13]);
    const float cm2 = 0.25f * (hr[2] + hr[6] + hr[10] + hr[14]);
    const float cm3 = 0.25f * (hr[3] + hr[7] + hr[11] + hr[15]);
    const float hps = 0.25f * (hp4[0] + hp4[1] + hp4[2] + hp4[3]);
    const float* xb = xs + (size_t)gr * SD + bn0;
    float* um = outMean + (size_t)gr * 1024 + bn0;
    float* uu = outUpd + (size_t)gr * 4096 + bn0;
#pragma unroll
    for (int k2i = 0; k2i < 4; ++k2i) {
      const int col = c0 + k2i * 32;
      f32x4 ov = *(const f32x4*)(EP + rr2 * 132 + col);
      ov += *(const f32x4*)(blayer + bn0 + col);
      const f32x4 x0 = *(const f32x4*)(xb + col);
      const f32x4 x1 = *(const f32x4*)(xb + 1024 + col);
      const f32x4 x2 = *(const f32x4*)(xb + 2048 + col);
      const f32x4 x3 = *(const f32x4*)(xb + 3072 + col);
      __builtin_nontemporal_store(cm0 * x0 + cm1 * x1 + cm2 * x2 + cm3 * x3 + ov * hps,
                                  (f32x4*)(um + col));
      __builtin_nontemporal_store(hr[0] * x0 + hr[1] * x1 + hr[2] * x2 + hr[3] * x3 + ov * hp4[0],
                                  (f32x4*)(uu + col));
      __builtin_nontemporal_store(hr[4] * x0 + hr[5] * x1 + hr[6] * x2 + hr[7] * x3 + ov * hp4[1],
                                  (f32x4*)(uu + 1024 + col));
      __builtin_nontemporal_store(hr[8] * x0 + hr[9] * x1 + hr[10] * x2 + hr[11] * x3 + ov * hp4[2],
                                  (f32x4*)(uu + 2048 + col));
      __builtin_nontemporal_store(hr[12] * x0 + hr[13] * x1 + hr[14] * x2 + hr[15] * x3 + ov * hp4[3],
                                  (f32x4*)(uu + 3072 + col));
    }
  }
}

// ---------------- launch ----------------
extern "C" void kernel_launch(void* const* d_in, const int* in_sizes, int n_in,
                              void* d_out, int out_size, void* d_ws, size_t ws_size,
                              hipStream_t stream) {
  const float* xs = (const float*)d_in[1];
  const float* Wpre = (const float*)d_in[2];
  const float* bpre = (const float*)d_in[3];
  const float* Wpost = (const float*)d_in[4];
  const float* bpost = (const float*)d_in[5];
  const float* Wres = (const float*)d_in[6];
  const float* bres = (const float*)d_in[7];
  const float* apre = (const float*)d_in[8];
  const float* apost = (const float*)d_in[9];
  const float* ares = (const float*)d_in[10];
  const float* gamma = (const float*)d_in[11];
  const float* beta = (const float*)d_in[12];
  const float* Wlayer = (const float*)d_in[13];
  const float* blayer = (const float*)d_in[14];

  const size_t OFF_LNAGG = (size_t)2 << 20;                     // 16 MB
  const size_t OFF_HRES = (size_t)18 << 20;                     // 512 KB
  const size_t OFF_HPOST = OFF_HRES + (size_t)BROWS * 16 * 4;   // 128 KB
  const size_t OFF_WSUM = OFF_HPOST + (size_t)BROWS * 4 * 4;    // 512 B
  const size_t OFF_WALL = OFF_WSUM + 512;                       // 384 KB
  const size_t NEED = OFF_WALL + (size_t)24 * SD * 4;
  if (ws_size < NEED) return;  // workspace too small — fail visibly

  char* ws = (char*)d_ws;
  unsigned short* wl16 = (unsigned short*)ws;
  unsigned short* lnagg = (unsigned short*)(ws + OFF_LNAGG);
  float* hresb = (float*)(ws + OFF_HRES);
  float* hpostb = (float*)(ws + OFF_HPOST);
  float* wsum = (float*)(ws + OFF_WSUM);
  float* Wall = (float*)(ws + OFF_WALL);

  float* outMean = (float*)d_out;
  float* outUpd = outMean + (size_t)BROWS * D;

  hipLaunchKernelGGL(k0_prep, dim3(1048), dim3(256), 0, stream, Wlayer, Wpre, Wpost, Wres,
                     wl16, Wall, wsum);
  hipLaunchKernelGGL(k1_rowpass, dim3(1024), dim3(512), 0, stream, xs, Wall, bpre, bpost,
                     bres, apre, apost, ares, gamma, beta, wsum, lnagg, hresb, hpostb);
  hipLaunchKernelGGL(k2_gemm_ep, dim3(64, 8), dim3(256), 0, stream, lnagg, wl16, blayer, xs,
                     hresb, hpostb, outMean, outUpd);
}

// Round 3
// 551.040 us; speedup vs baseline: 1.4419x; 1.4419x over previous
//
#include <hip/hip_runtime.h>

#define DEV __device__ __forceinline__

typedef __bf16 bf16x8 __attribute__((ext_vector_type(8)));
typedef float f32x4 __attribute__((ext_vector_type(4)));
typedef unsigned int u32;

constexpr int BROWS = 8192;
constexpr int D = 1024;
constexpr int SD = 4096;

// ---------------- helpers ----------------
DEV unsigned short f2bf(float f) {  // RNE float->bf16
  unsigned int u = __float_as_uint(f);
  u = (u + 0x7FFFu + ((u >> 16) & 1u)) >> 16;
  return (unsigned short)u;
}

DEV float wred(float v) {  // full 64-lane butterfly sum (result in all lanes)
#pragma unroll
  for (int m = 1; m < 64; m <<= 1) v += __shfl_xor(v, m);
  return v;
}

DEV float sigmoidf(float x) { return 1.0f / (1.0f + __expf(-x)); }

DEV void async_ld16(const void* g, void* l) {  // 16B global -> LDS DMA
  __builtin_amdgcn_global_load_lds((const __attribute__((address_space(1))) u32*)g,
                                   (__attribute__((address_space(3))) u32*)l, 16, 0, 0);
}

// ---------------- K0: prep — W_layer->bf16, pack 24 gate rows, row-sums ----
__global__ __launch_bounds__(256) void k0_prep(
    const float* __restrict__ Wlayer, const float* __restrict__ Wpre,
    const float* __restrict__ Wpost, const float* __restrict__ Wres,
    unsigned short* __restrict__ wl16, float* __restrict__ Wall,
    float* __restrict__ wsum) {
  const int bx = blockIdx.x, tid = threadIdx.x;
  if (bx < 1024) {  // W_layer fp32 -> bf16
    const int i = bx * 1024 + tid * 4;
    float4 v = *(const float4*)(Wlayer + i);
    ushort4 u = make_ushort4(f2bf(v.x), f2bf(v.y), f2bf(v.z), f2bf(v.w));
    *(ushort4*)(wl16 + i) = u;
  } else {  // pack gate row j into Wall + row-sum
    const int j = bx - 1024;  // 0..23
    const float* src = (j < 4) ? (Wpre + j * SD)
                               : (j < 8 ? (Wpost + (j - 4) * SD) : (Wres + (j - 8) * SD));
    float s = 0.f;
    for (int i = tid * 4; i < SD; i += 1024) {
      float4 v = *(const float4*)(src + i);
      *(float4*)(Wall + j * SD + i) = v;
      s += v.x + v.y + v.z + v.w;
    }
    s = wred(s);
    __shared__ float tmp[4];
    if ((tid & 63) == 0) tmp[tid >> 6] = s;
    __syncthreads();
    if (tid == 0) wsum[j] = tmp[0] + tmp[1] + tmp[2] + tmp[3];
  }
}

// ---------------- K1: fused per-row pass, LDS-staged pipelined ----------------
// Block = 8 rows, 8 waves (512 thr). x DMA'd (global_load_lds) into a 4-slot
// LDS ring; ALL waves read x from LDS. Wave w: dots j in [3w,3w+3) for all 8
// rows (acc[3][8]=24 regs) + stats for row w only (2 regs). W double-buffered
// in regs (2x3 float4 = 24 regs) from L2-hot Wall.
// NOTE: NO min-waves arg in __launch_bounds__ — rounds 1/2 proved the second
// arg caps VGPRs (84/64) and spills the pipeline state to scratch
// (WRITE_SIZE 536/959 MB). Need-based allocation (~100-130 regs) -> no spill,
// ~4 waves/SIMD.
// Sync per K-step: counted s_waitcnt vmcnt(N) + raw s_barrier, never vmcnt(0).
// FIFO per iter i: issue W(i+1) x3, DMA(i+2) x1 -> newer-than-DMA(i) = 8.
// (Compiler inserts its own tighter vmcnt before CMP's use of W regs; that
// wait still leaves the in-flight DMAs outstanding.)
// lgkmcnt(0) before each barrier drains ds_reads -> WAR on ring slots closed
// (slot reused after 4 steps >> 1 barrier of wave skew).
__global__ __launch_bounds__(512) void k1_rowpass(
    const float* __restrict__ xs, const float* __restrict__ Wall,
    const float* __restrict__ bpre, const float* __restrict__ bpost,
    const float* __restrict__ bres,
    const float* __restrict__ s_apre, const float* __restrict__ s_apost,
    const float* __restrict__ s_ares,
    const float* __restrict__ gamma, const float* __restrict__ beta,
    const float* __restrict__ wsum,
    unsigned short* __restrict__ lnagg,
    float* __restrict__ hres_g, float* __restrict__ hpost_g) {
  const int tid = threadIdx.x;
  const int wv = tid >> 6;   // 0..7
  const int ln = tid & 63;
  const int rb = blockIdx.x * 8;
  const int l4 = ln * 4;

  __shared__ float XR[4][8][256];  // 32 KB x ring: [slot][row][k-chunk]
  __shared__ float DOT[24][8];
  __shared__ float MU[8];
  __shared__ float RSH[8];
  __shared__ float HPRE[8][4];
  float* XR0 = &XR[0][0][0];

  const int jb = wv * 3;
  const float* Wb = Wall + (size_t)jb * SD;
  // DMA: wave w stages row w. LDS dest = slot base + tid*16B -> row tid>>6=wv,
  // col (tid&63)*4 = l4 — matches the contiguity contract of global_load_lds.
  const float* gx = xs + (size_t)(rb + wv) * SD + l4;

  float acc[3][8];
#pragma unroll
  for (int q = 0; q < 3; ++q)
#pragma unroll
    for (int r = 0; r < 8; ++r) acc[q][r] = 0.f;
  float s2 = 0.f, q2 = 0.f;  // stats for row wv

  float4 wbufA[3], wbufB[3];

#define LDW(dst, it)                                                      \
  {                                                                       \
    const float* p_ = Wb + (it) * 256 + l4;                               \
    _Pragma("unroll") for (int q = 0; q < 3; ++q) dst[q] =                \
        *(const float4*)(p_ + (size_t)q * SD);                            \
  }
#define DMA1(it)                                                          \
  async_ld16(gx + (it) * 256, XR0 + ((it) & 3) * 2048 + tid * 4);
#define CMP(it, W)                                                        \
  {                                                                       \
    const int so_ = ((it) & 3) * 2048;                                    \
    float4 sv_ = *(const float4*)(XR0 + so_ + wv * 256 + l4);             \
    s2 += sv_.x + sv_.y + sv_.z + sv_.w;                                  \
    q2 += sv_.x * sv_.x + sv_.y * sv_.y + sv_.z * sv_.z + sv_.w * sv_.w;  \
    _Pragma("unroll") for (int r = 0; r < 8; ++r) {                       \
      float4 xv_ = *(const float4*)(XR0 + so_ + r * 256 + l4);            \
      _Pragma("unroll") for (int q = 0; q < 3; ++q) acc[q][r] +=          \
          W[q].x * xv_.x + W[q].y * xv_.y + W[q].z * xv_.z +              \
          W[q].w * xv_.w;                                                 \
    }                                                                     \
  }
#define KSTEP(I, WCUR, WNXT, LIT, DOW, DODMA)                             \
  {                                                                       \
    if (DOW) LDW(WNXT, (I) + 1);                                          \
    if (DODMA) DMA1((I) + 2);                                             \
    asm volatile("s_waitcnt vmcnt(" LIT ") lgkmcnt(0)" ::: "memory");     \
    __builtin_amdgcn_s_barrier();                                         \
    asm volatile("" ::: "memory");                                        \
    CMP(I, WCUR);                                                         \
  }

  // prologue (fenced so the vmcnt FIFO counts are exact)
  DMA1(0);
  DMA1(1);
  asm volatile("" ::: "memory");
  LDW(wbufA, 0);

  KSTEP(0, wbufA, wbufB, "8", 1, 1)
#pragma unroll
  for (int i = 1; i <= 11; i += 2) {
    KSTEP(i, wbufB, wbufA, "8", 1, 1)
    KSTEP(i + 1, wbufA, wbufB, "8", 1, 1)
  }
  KSTEP(13, wbufB, wbufA, "8", 1, 1)
  KSTEP(14, wbufA, wbufB, "7", 1, 0)
  KSTEP(15, wbufB, wbufA, "3", 0, 0)
#undef KSTEP
#undef CMP
#undef DMA1
#undef LDW

  // ---- reductions (butterfly; result in all lanes) ----
#pragma unroll
  for (int q = 0; q < 3; ++q)
#pragma unroll
    for (int r = 0; r < 8; ++r) acc[q][r] = wred(acc[q][r]);
  s2 = wred(s2);
  q2 = wred(q2);

  if (ln == 0) {
#pragma unroll
    for (int q = 0; q < 3; ++q)
#pragma unroll
      for (int r = 0; r < 8; ++r) DOT[jb + q][r] = acc[q][r];
    const float mu = s2 * (1.0f / 4096.0f);
    MU[wv] = mu;
    RSH[wv] = rsqrtf(q2 * (1.0f / 4096.0f) - mu * mu + 1e-5f);
  }
  __syncthreads();

  // ---- gates ----
  if (wv < 2) {  // sinkhorn: wave w -> rows 4w..4w+3; 64 lanes = 4 rows x 16
    const float ares = s_ares[0];
    const int rr = (wv << 2) + (ln >> 4), jj = ln & 15;
    const float corr = RSH[rr] * (DOT[8 + jj][rr] - MU[rr] * wsum[8 + jj]);
    float M = __expf(ares * (corr + bres[jj]));
#pragma unroll 1
    for (int itr = 0; itr < 20; ++itr) {
      float rs_ = M + __shfl_xor(M, 1);
      rs_ += __shfl_xor(rs_, 2);
      M *= __builtin_amdgcn_rcpf(rs_ + 1e-8f);
      float cs = M + __shfl_xor(M, 4);
      cs += __shfl_xor(cs, 8);
      M *= __builtin_amdgcn_rcpf(cs + 1e-8f);
    }
    hres_g[(size_t)(rb + rr) * 16 + jj] = M;
  } else if (wv == 2) {
    if (ln < 32) {
      const int r = ln >> 2, s = ln & 3;
      const float corr = RSH[r] * (DOT[s][r] - MU[r] * wsum[s]);
      HPRE[r][s] = sigmoidf(s_apre[0] * (corr + bpre[s]));
    }
  } else if (wv == 3) {
    if (ln < 32) {
      const int r = ln >> 2, s = ln & 3;
      const float corr = RSH[r] * (DOT[4 + s][r] - MU[r] * wsum[4 + s]);
      hpost_g[(size_t)(rb + r) * 4 + s] = 2.0f * sigmoidf(s_apost[0] * (corr + bpost[s]));
    }
  }
  __syncthreads();

  // ---- phase 2: x_agg + LN + bf16 store — wave w owns row rb+w
  // (x re-read hits L2/L3: FETCH_SIZE confirms ~1x x total)
  {
    const int b = rb + wv;
    const float* xb = xs + (size_t)b * SD;
    const float h0 = HPRE[wv][0], h1 = HPRE[wv][1], h2 = HPRE[wv][2], h3 = HPRE[wv][3];
    float4 agg[4];
    float asum = 0.f, asq = 0.f;
#pragma unroll
    for (int i2 = 0; i2 < 4; ++i2) {
      const int d = i2 * 256 + l4;
      float4 g0 = *(const float4*)(xb + d);
      float4 g1 = *(const float4*)(xb + D + d);
      float4 g2 = *(const float4*)(xb + 2 * D + d);
      float4 g3 = *(const float4*)(xb + 3 * D + d);
      float4 a;
      a.x = h0 * g0.x + h1 * g1.x + h2 * g2.x + h3 * g3.x;
      a.y = h0 * g0.y + h1 * g1.y + h2 * g2.y + h3 * g3.y;
      a.z = h0 * g0.z + h1 * g1.z + h2 * g2.z + h3 * g3.z;
      a.w = h0 * g0.w + h1 * g1.w + h2 * g2.w + h3 * g3.w;
      agg[i2] = a;
      asum += a.x + a.y + a.z + a.w;
      asq += a.x * a.x + a.y * a.y + a.z * a.z + a.w * a.w;
    }
    asum = wred(asum);
    asq = wred(asq);
    const float mu2 = asum * (1.0f / 1024.0f);
    const float rstd2 = rsqrtf(asq * (1.0f / 1024.0f) - mu2 * mu2 + 1e-5f);
#pragma unroll
    for (int i2 = 0; i2 < 4; ++i2) {
      const int d = i2 * 256 + l4;
      float4 g = *(const float4*)(gamma + d);
      float4 bb = *(const float4*)(beta + d);
      ushort4 u;
      u.x = f2bf((agg[i2].x - mu2) * rstd2 * g.x + bb.x);
      u.y = f2bf((agg[i2].y - mu2) * rstd2 * g.y + bb.y);
      u.z = f2bf((agg[i2].z - mu2) * rstd2 * g.z + bb.z);
      u.w = f2bf((agg[i2].w - mu2) * rstd2 * g.w + bb.w);
      *(ushort4*)(lnagg + (size_t)b * D + d) = u;
    }
  }
}

// ---------------- K2: bf16 MFMA GEMM + fused epilogue ----------------
__global__ __launch_bounds__(256) void k2_gemm_ep(
    const unsigned short* __restrict__ A,   // lnagg bf16 [8192][1024]
    const unsigned short* __restrict__ Bw,  // W_layer bf16 [1024][1024]
    const float* __restrict__ blayer,
    const float* __restrict__ xs,
    const float* __restrict__ hres_g, const float* __restrict__ hpost_g,
    float* __restrict__ outMean, float* __restrict__ outUpd) {
  __shared__ char smem[44032];
  char* AsB = smem;            // 16384 B: 128 rows x 64 bf16 (8 chunks of 16B)
  char* BsB = smem + 16384;    // 16384 B
  float* EP = (float*)smem;    // epilogue overlay: 32 x 132 fp32 = 16896 B
  float* HR = (float*)(smem + 32768);  // 128 x 17
  float* HP = (float*)(smem + 41472);  // 128 x 5

  const int tid = threadIdx.x;
  const int l = tid & 63;
  const int wv = tid >> 6;
  const int wm = wv >> 1, wn = wv & 1;
  const int lrow = l & 15, lq = l >> 4;
  const int bm0 = blockIdx.x * 128;
  const int bn0 = blockIdx.y * 128;

#pragma unroll
  for (int i = 0; i < 8; ++i) {
    int idx = i * 256 + tid;  // 0..2047
    HR[(idx >> 4) * 17 + (idx & 15)] = hres_g[(size_t)bm0 * 16 + idx];
  }
#pragma unroll
  for (int i = 0; i < 2; ++i) {
    int idx = i * 256 + tid;  // 0..511
    HP[(idx >> 2) * 5 + (idx & 3)] = hpost_g[(size_t)bm0 * 4 + idx];
  }

  f32x4 acc[4][4] = {};

#pragma unroll 1
  for (int kt = 0; kt < 16; ++kt) {
    __syncthreads();
#pragma unroll
    for (int c = 0; c < 4; ++c) {
      const int idx = c * 256 + tid;              // 16B-chunk index 0..1023
      const int row = idx >> 3, cc = idx & 7;
      const int gch = cc ^ (row & 7);             // XOR swizzle on global side
      async_ld16((const char*)A + ((size_t)(bm0 + row) << 11) + kt * 128 + gch * 16,
                 AsB + idx * 16);
      async_ld16((const char*)Bw + ((size_t)(bn0 + row) << 11) + kt * 128 + gch * 16,
                 BsB + idx * 16);
    }
    __syncthreads();
#pragma unroll
    for (int kk = 0; kk < 2; ++kk) {
      bf16x8 af[4], bfr[4];
      const int sw = (kk * 4 + lq);
#pragma unroll
      for (int t = 0; t < 4; ++t) {
        const int ra = wm * 64 + t * 16 + lrow;
        const int rbr = wn * 64 + t * 16 + lrow;
        af[t] = *(const bf16x8*)(AsB + ra * 128 + (sw ^ (ra & 7)) * 16);
        bfr[t] = *(const bf16x8*)(BsB + rbr * 128 + (sw ^ (rbr & 7)) * 16);
      }
#pragma unroll
      for (int ti = 0; ti < 4; ++ti)
#pragma unroll
        for (int tj = 0; tj < 4; ++tj)
          acc[ti][tj] =
              __builtin_amdgcn_mfma_f32_16x16x32_bf16(af[ti], bfr[tj], acc[ti][tj], 0, 0, 0);
    }
  }

  // ---- epilogue: 4 chunks of 32 rows; LDS transpose then nt-vector stream
#pragma unroll
  for (int ti = 0; ti < 4; ++ti) {
    __syncthreads();
#pragma unroll
    for (int tj = 0; tj < 4; ++tj)
#pragma unroll
      for (int r2 = 0; r2 < 4; ++r2)
        EP[(wm * 16 + lq * 4 + r2) * 132 + wn * 64 + tj * 16 + lrow] = acc[ti][tj][r2];
    __syncthreads();

    const int rr2 = tid >> 3;        // 0..31
    const int c0 = (tid & 7) * 4;    // first float4 col, stride 32 over k2i
    const int bl = (rr2 >> 4) * 64 + ti * 16 + (rr2 & 15);
    const int gr = bm0 + bl;
    float hr[16], hp4[4];
#pragma unroll
    for (int q = 0; q < 16; ++q) hr[q] = HR[bl * 17 + q];
#pragma unroll
    for (int q = 0; q < 4; ++q) hp4[q] = HP[bl * 5 + q];
    const float cm0 = 0.25f * (hr[0] + hr[4] + hr[8] + hr[12]);
    const float cm1 = 0.25f * (hr[1] + hr[5] + hr[9] + hr[13]);
    const float cm2 = 0.25f * (hr[2] + hr[6] + hr[10] + hr[14]);
    const float cm3 = 0.25f * (hr[3] + hr[7] + hr[11] + hr[15]);
    const float hps = 0.25f * (hp4[0] + hp4[1] + hp4[2] + hp4[3]);
    const float* xb = xs + (size_t)gr * SD + bn0;
    float* um = outMean + (size_t)gr * 1024 + bn0;
    float* uu = outUpd + (size_t)gr * 4096 + bn0;
#pragma unroll
    for (int k2i = 0; k2i < 4; ++k2i) {
      const int col = c0 + k2i * 32;
      f32x4 ov = *(const f32x4*)(EP + rr2 * 132 + col);
      ov += *(const f32x4*)(blayer + bn0 + col);
      const f32x4 x0 = *(const f32x4*)(xb + col);
      const f32x4 x1 = *(const f32x4*)(xb + 1024 + col);
      const f32x4 x2 = *(const f32x4*)(xb + 2048 + col);
      const f32x4 x3 = *(const f32x4*)(xb + 3072 + col);
      __builtin_nontemporal_store(cm0 * x0 + cm1 * x1 + cm2 * x2 + cm3 * x3 + ov * hps,
                                  (f32x4*)(um + col));
      __builtin_nontemporal_store(hr[0] * x0 + hr[1] * x1 + hr[2] * x2 + hr[3] * x3 + ov * hp4[0],
                                  (f32x4*)(uu + col));
      __builtin_nontemporal_store(hr[4] * x0 + hr[5] * x1 + hr[6] * x2 + hr[7] * x3 + ov * hp4[1],
                                  (f32x4*)(uu + 1024 + col));
      __builtin_nontemporal_store(hr[8] * x0 + hr[9] * x1 + hr[10] * x2 + hr[11] * x3 + ov * hp4[2],
                                  (f32x4*)(uu + 2048 + col));
      __builtin_nontemporal_store(hr[12] * x0 + hr[13] * x1 + hr[14] * x2 + hr[15] * x3 + ov * hp4[3],
                                  (f32x4*)(uu + 3072 + col));
    }
  }
}

// ---------------- launch ----------------
extern "C" void kernel_launch(void* const* d_in, const int* in_sizes, int n_in,
                              void* d_out, int out_size, void* d_ws, size_t ws_size,
                              hipStream_t stream) {
  const float* xs = (const float*)d_in[1];
  const float* Wpre = (const float*)d_in[2];
  const float* bpre = (const float*)d_in[3];
  const float* Wpost = (const float*)d_in[4];
  const float* bpost = (const float*)d_in[5];
  const float* Wres = (const float*)d_in[6];
  const float* bres = (const float*)d_in[7];
  const float* apre = (const float*)d_in[8];
  const float* apost = (const float*)d_in[9];
  const float* ares = (const float*)d_in[10];
  const float* gamma = (const float*)d_in[11];
  const float* beta = (const float*)d_in[12];
  const float* Wlayer = (const float*)d_in[13];
  const float* blayer = (const float*)d_in[14];

  const size_t OFF_LNAGG = (size_t)2 << 20;                     // 16 MB
  const size_t OFF_HRES = (size_t)18 << 20;                     // 512 KB
  const size_t OFF_HPOST = OFF_HRES + (size_t)BROWS * 16 * 4;   // 128 KB
  const size_t OFF_WSUM = OFF_HPOST + (size_t)BROWS * 4 * 4;    // 512 B
  const size_t OFF_WALL = OFF_WSUM + 512;                       // 384 KB
  const size_t NEED = OFF_WALL + (size_t)24 * SD * 4;
  if (ws_size < NEED) return;  // workspace too small — fail visibly

  char* ws = (char*)d_ws;
  unsigned short* wl16 = (unsigned short*)ws;
  unsigned short* lnagg = (unsigned short*)(ws + OFF_LNAGG);
  float* hresb = (float*)(ws + OFF_HRES);
  float* hpostb = (float*)(ws + OFF_HPOST);
  float* wsum = (float*)(ws + OFF_WSUM);
  float* Wall = (float*)(ws + OFF_WALL);

  float* outMean = (float*)d_out;
  float* outUpd = outMean + (size_t)BROWS * D;

  hipLaunchKernelGGL(k0_prep, dim3(1048), dim3(256), 0, stream, Wlayer, Wpre, Wpost, Wres,
                     wl16, Wall, wsum);
  hipLaunchKernelGGL(k1_rowpass, dim3(1024), dim3(512), 0, stream, xs, Wall, bpre, bpost,
                     bres, apre, apost, ares, gamma, beta, wsum, lnagg, hresb, hpostb);
  hipLaunchKernelGGL(k2_gemm_ep, dim3(64, 8), dim3(256), 0, stream, lnagg, wl16, blayer, xs,
                     hresb, hpostb, outMean, outUpd);
}

// Round 4
// 414.484 us; speedup vs baseline: 1.9170x; 1.3295x over previous
//
#include <hip/hip_runtime.h>

#define DEV __device__ __forceinline__

typedef __bf16 bf16x8 __attribute__((ext_vector_type(8)));
typedef float f32x4 __attribute__((ext_vector_type(4)));
typedef unsigned int u32;

constexpr int BROWS = 8192;
constexpr int D = 1024;
constexpr int SD = 4096;

// ---------------- helpers ----------------
DEV unsigned short f2bf(float f) {  // RNE float->bf16
  unsigned int u = __float_as_uint(f);
  u = (u + 0x7FFFu + ((u >> 16) & 1u)) >> 16;
  return (unsigned short)u;
}

DEV float wred(float v) {  // full 64-lane butterfly sum (result in all lanes)
#pragma unroll
  for (int m = 1; m < 64; m <<= 1) v += __shfl_xor(v, m);
  return v;
}

DEV float sigmoidf(float x) { return 1.0f / (1.0f + __expf(-x)); }

DEV void async_ld16(const void* g, void* l) {  // 16B global -> LDS DMA
  __builtin_amdgcn_global_load_lds((const __attribute__((address_space(1))) u32*)g,
                                   (__attribute__((address_space(3))) u32*)l, 16, 0, 0);
}

// ---------------- K0: prep — W_layer->bf16, pack 24 gate rows, row-sums ----
__global__ __launch_bounds__(256) void k0_prep(
    const float* __restrict__ Wlayer, const float* __restrict__ Wpre,
    const float* __restrict__ Wpost, const float* __restrict__ Wres,
    unsigned short* __restrict__ wl16, float* __restrict__ Wall,
    float* __restrict__ wsum) {
  const int bx = blockIdx.x, tid = threadIdx.x;
  if (bx < 1024) {  // W_layer fp32 -> bf16
    const int i = bx * 1024 + tid * 4;
    float4 v = *(const float4*)(Wlayer + i);
    ushort4 u = make_ushort4(f2bf(v.x), f2bf(v.y), f2bf(v.z), f2bf(v.w));
    *(ushort4*)(wl16 + i) = u;
  } else {  // pack gate row j into Wall + row-sum
    const int j = bx - 1024;  // 0..23
    const float* src = (j < 4) ? (Wpre + j * SD)
                               : (j < 8 ? (Wpost + (j - 4) * SD) : (Wres + (j - 8) * SD));
    float s = 0.f;
    for (int i = tid * 4; i < SD; i += 1024) {
      float4 v = *(const float4*)(src + i);
      *(float4*)(Wall + j * SD + i) = v;
      s += v.x + v.y + v.z + v.w;
    }
    s = wred(s);
    __shared__ float tmp[4];
    if ((tid & 63) == 0) tmp[tid >> 6] = s;
    __syncthreads();
    if (tid == 0) wsum[j] = tmp[0] + tmp[1] + tmp[2] + tmp[3];
  }
}

// ---------------- K1: fused per-row pass, LDS-staged pipelined ----------------
// Block = 8 rows, 8 waves (512 thr). x DMA'd (global_load_lds) into a 4-slot
// LDS ring; ALL waves read x from LDS. Wave w: dots j in [3w,3w+3) for all 8
// rows (acc[3][8]) + stats for row w (folded into the r==wv iteration).
// W double-buffered in regs from L2-hot Wall.
// Register-pressure lessons (rounds 1-3):
//  * launch_bounds 2nd arg capped VGPR (84/64) -> scratch spill, 0.5-1 GB
//    WRITE_SIZE. Removed.
//  * Fully-unrolled 16-step loop materialized per-step 64b addresses ->
//    demand > the allocator's 128 heuristic -> spilled one W buffer per step
//    (373 MB writes). Fix: RUNTIME 2-step body (7 iters) + peeled steps 14/15,
//    plus amdgpu_waves_per_eu(2) so the allocator grows past 128 instead of
//    spilling if demand lands slightly above.
// Sync per K-step: counted s_waitcnt vmcnt(N) + raw s_barrier, never vmcnt(0).
// FIFO (simulated for this ordering): steady queue before the wait =
// [D(i), W(i)x3, D(i+1), W(i+1)x3, D(i+2)] = 9 -> vmcnt(8) retires exactly
// D(i); compiler auto-waitcnt covers the W-register dependency (vmcnt<=4).
// Peeled: step14 queue=8 -> vmcnt(7); step15 queue=4 -> vmcnt(3).
// lgkmcnt(0) before each barrier drains ds_reads -> WAR on ring slots closed.
__global__ __launch_bounds__(512) __attribute__((amdgpu_waves_per_eu(2)))
void k1_rowpass(
    const float* __restrict__ xs, const float* __restrict__ Wall,
    const float* __restrict__ bpre, const float* __restrict__ bpost,
    const float* __restrict__ bres,
    const float* __restrict__ s_apre, const float* __restrict__ s_apost,
    const float* __restrict__ s_ares,
    const float* __restrict__ gamma, const float* __restrict__ beta,
    const float* __restrict__ wsum,
    unsigned short* __restrict__ lnagg,
    float* __restrict__ hres_g, float* __restrict__ hpost_g) {
  const int tid = threadIdx.x;
  const int wv = tid >> 6;   // 0..7
  const int ln = tid & 63;
  const int rb = blockIdx.x * 8;
  const int l4 = ln * 4;

  __shared__ float XR[4][8][256];  // 32 KB x ring: [slot][row][k-chunk]
  __shared__ float DOT[24][8];
  __shared__ float MU[8];
  __shared__ float RSH[8];
  __shared__ float HPRE[8][4];
  float* XR0 = &XR[0][0][0];

  const int jb = wv * 3;
  const float* Wb = Wall + (size_t)jb * SD;
  // DMA: wave w stages row w. Per-lane dest = slot base + tid*16B -> row
  // tid>>6 = wv, col (tid&63)*4 — matches global_load_lds's lane-linear
  // contract and the global source row.
  const float* gx = xs + (size_t)(rb + wv) * SD + l4;

  float acc[3][8];
#pragma unroll
  for (int q = 0; q < 3; ++q)
#pragma unroll
    for (int r = 0; r < 8; ++r) acc[q][r] = 0.f;
  float s2 = 0.f, q2 = 0.f;  // stats for row wv

  float4 wbufA[3], wbufB[3];

#define LDW(dst, it)                                                      \
  {                                                                       \
    const float* p_ = Wb + (it) * 256 + l4;                               \
    _Pragma("unroll") for (int q = 0; q < 3; ++q) dst[q] =                \
        *(const float4*)(p_ + (size_t)q * SD);                            \
  }
#define DMA1(it)                                                          \
  async_ld16(gx + (it) * 256, XR0 + ((it) & 3) * 2048 + tid * 4);
#define CMP(it, W)                                                        \
  {                                                                       \
    const int so_ = ((it) & 3) * 2048;                                    \
    _Pragma("unroll") for (int r = 0; r < 8; ++r) {                       \
      float4 xv_ = *(const float4*)(XR0 + so_ + r * 256 + l4);            \
      if (r == wv) { /* wave-uniform branch: stats for own row */         \
        s2 += xv_.x + xv_.y + xv_.z + xv_.w;                              \
        q2 += xv_.x * xv_.x + xv_.y * xv_.y + xv_.z * xv_.z +             \
              xv_.w * xv_.w;                                              \
      }                                                                   \
      _Pragma("unroll") for (int q = 0; q < 3; ++q) acc[q][r] +=          \
          W[q].x * xv_.x + W[q].y * xv_.y + W[q].z * xv_.z +              \
          W[q].w * xv_.w;                                                 \
    }                                                                     \
  }
#define WAITB(LIT)                                                        \
  asm volatile("s_waitcnt vmcnt(" LIT ") lgkmcnt(0)" ::: "memory");       \
  __builtin_amdgcn_s_barrier();                                           \
  asm volatile("" ::: "memory");

  // prologue (fenced so the vmcnt FIFO counts are exact)
  DMA1(0);
  DMA1(1);
  asm volatile("" ::: "memory");
  LDW(wbufA, 0);

#pragma unroll 1
  for (int it = 0; it < 14; it += 2) {  // steps 0..13, runtime addresses
    LDW(wbufB, it + 1);
    DMA1(it + 2);
    WAITB("8")
    CMP(it, wbufA);
    LDW(wbufA, it + 2);
    DMA1(it + 3);
    WAITB("8")
    CMP(it + 1, wbufB);
  }
  // peeled: step 14 (no DMA), step 15 (no issues)
  LDW(wbufB, 15);
  WAITB("7")
  CMP(14, wbufA);
  WAITB("3")
  CMP(15, wbufB);
#undef WAITB
#undef CMP
#undef DMA1
#undef LDW

  // ---- reductions (butterfly; result in all lanes) ----
#pragma unroll
  for (int q = 0; q < 3; ++q)
#pragma unroll
    for (int r = 0; r < 8; ++r) acc[q][r] = wred(acc[q][r]);
  s2 = wred(s2);
  q2 = wred(q2);

  if (ln == 0) {
#pragma unroll
    for (int q = 0; q < 3; ++q)
#pragma unroll
      for (int r = 0; r < 8; ++r) DOT[jb + q][r] = acc[q][r];
    const float mu = s2 * (1.0f / 4096.0f);
    MU[wv] = mu;
    RSH[wv] = rsqrtf(q2 * (1.0f / 4096.0f) - mu * mu + 1e-5f);
  }
  __syncthreads();

  // ---- gates ----
  if (wv < 2) {  // sinkhorn: wave w -> rows 4w..4w+3; 64 lanes = 4 rows x 16
    const float ares = s_ares[0];
    const int rr = (wv << 2) + (ln >> 4), jj = ln & 15;
    const float corr = RSH[rr] * (DOT[8 + jj][rr] - MU[rr] * wsum[8 + jj]);
    float M = __expf(ares * (corr + bres[jj]));
#pragma unroll 1
    for (int itr = 0; itr < 20; ++itr) {
      float rs_ = M + __shfl_xor(M, 1);
      rs_ += __shfl_xor(rs_, 2);
      M *= __builtin_amdgcn_rcpf(rs_ + 1e-8f);
      float cs = M + __shfl_xor(M, 4);
      cs += __shfl_xor(cs, 8);
      M *= __builtin_amdgcn_rcpf(cs + 1e-8f);
    }
    hres_g[(size_t)(rb + rr) * 16 + jj] = M;
  } else if (wv == 2) {
    if (ln < 32) {
      const int r = ln >> 2, s = ln & 3;
      const float corr = RSH[r] * (DOT[s][r] - MU[r] * wsum[s]);
      HPRE[r][s] = sigmoidf(s_apre[0] * (corr + bpre[s]));
    }
  } else if (wv == 3) {
    if (ln < 32) {
      const int r = ln >> 2, s = ln & 3;
      const float corr = RSH[r] * (DOT[4 + s][r] - MU[r] * wsum[4 + s]);
      hpost_g[(size_t)(rb + r) * 4 + s] = 2.0f * sigmoidf(s_apost[0] * (corr + bpost[s]));
    }
  }
  __syncthreads();

  // ---- phase 2: x_agg + LN + bf16 store — wave w owns row rb+w
  // (x re-read hits L2: block's 32 KB was just fetched)
  {
    const int b = rb + wv;
    const float* xb = xs + (size_t)b * SD;
    const float h0 = HPRE[wv][0], h1 = HPRE[wv][1], h2 = HPRE[wv][2], h3 = HPRE[wv][3];
    float4 agg[4];
    float asum = 0.f, asq = 0.f;
#pragma unroll
    for (int i2 = 0; i2 < 4; ++i2) {
      const int d = i2 * 256 + l4;
      float4 g0 = *(const float4*)(xb + d);
      float4 g1 = *(const float4*)(xb + D + d);
      float4 g2 = *(const float4*)(xb + 2 * D + d);
      float4 g3 = *(const float4*)(xb + 3 * D + d);
      float4 a;
      a.x = h0 * g0.x + h1 * g1.x + h2 * g2.x + h3 * g3.x;
      a.y = h0 * g0.y + h1 * g1.y + h2 * g2.y + h3 * g3.y;
      a.z = h0 * g0.z + h1 * g1.z + h2 * g2.z + h3 * g3.z;
      a.w = h0 * g0.w + h1 * g1.w + h2 * g2.w + h3 * g3.w;
      agg[i2] = a;
      asum += a.x + a.y + a.z + a.w;
      asq += a.x * a.x + a.y * a.y + a.z * a.z + a.w * a.w;
    }
    asum = wred(asum);
    asq = wred(asq);
    const float mu2 = asum * (1.0f / 1024.0f);
    const float rstd2 = rsqrtf(asq * (1.0f / 1024.0f) - mu2 * mu2 + 1e-5f);
#pragma unroll
    for (int i2 = 0; i2 < 4; ++i2) {
      const int d = i2 * 256 + l4;
      float4 g = *(const float4*)(gamma + d);
      float4 bb = *(const float4*)(beta + d);
      ushort4 u;
      u.x = f2bf((agg[i2].x - mu2) * rstd2 * g.x + bb.x);
      u.y = f2bf((agg[i2].y - mu2) * rstd2 * g.y + bb.y);
      u.z = f2bf((agg[i2].z - mu2) * rstd2 * g.z + bb.z);
      u.w = f2bf((agg[i2].w - mu2) * rstd2 * g.w + bb.w);
      *(ushort4*)(lnagg + (size_t)b * D + d) = u;
    }
  }
}

// ---------------- K2: bf16 MFMA GEMM + fused epilogue ----------------
__global__ __launch_bounds__(256) void k2_gemm_ep(
    const unsigned short* __restrict__ A,   // lnagg bf16 [8192][1024]
    const unsigned short* __restrict__ Bw,  // W_layer bf16 [1024][1024]
    const float* __restrict__ blayer,
    const float* __restrict__ xs,
    const float* __restrict__ hres_g, const float* __restrict__ hpost_g,
    float* __restrict__ outMean, float* __restrict__ outUpd) {
  __shared__ char smem[44032];
  char* AsB = smem;            // 16384 B: 128 rows x 64 bf16 (8 chunks of 16B)
  char* BsB = smem + 16384;    // 16384 B
  float* EP = (float*)smem;    // epilogue overlay: 32 x 132 fp32 = 16896 B
  float* HR = (float*)(smem + 32768);  // 128 x 17
  float* HP = (float*)(smem + 41472);  // 128 x 5

  const int tid = threadIdx.x;
  const int l = tid & 63;
  const int wv = tid >> 6;
  const int wm = wv >> 1, wn = wv & 1;
  const int lrow = l & 15, lq = l >> 4;
  const int bm0 = blockIdx.x * 128;
  const int bn0 = blockIdx.y * 128;

#pragma unroll
  for (int i = 0; i < 8; ++i) {
    int idx = i * 256 + tid;  // 0..2047
    HR[(idx >> 4) * 17 + (idx & 15)] = hres_g[(size_t)bm0 * 16 + idx];
  }
#pragma unroll
  for (int i = 0; i < 2; ++i) {
    int idx = i * 256 + tid;  // 0..511
    HP[(idx >> 2) * 5 + (idx & 3)] = hpost_g[(size_t)bm0 * 4 + idx];
  }

  f32x4 acc[4][4] = {};

#pragma unroll 1
  for (int kt = 0; kt < 16; ++kt) {
    __syncthreads();
#pragma unroll
    for (int c = 0; c < 4; ++c) {
      const int idx = c * 256 + tid;              // 16B-chunk index 0..1023
      const int row = idx >> 3, cc = idx & 7;
      const int gch = cc ^ (row & 7);             // XOR swizzle on global side
      async_ld16((const char*)A + ((size_t)(bm0 + row) << 11) + kt * 128 + gch * 16,
                 AsB + idx * 16);
      async_ld16((const char*)Bw + ((size_t)(bn0 + row) << 11) + kt * 128 + gch * 16,
                 BsB + idx * 16);
    }
    __syncthreads();
#pragma unroll
    for (int kk = 0; kk < 2; ++kk) {
      bf16x8 af[4], bfr[4];
      const int sw = (kk * 4 + lq);
#pragma unroll
      for (int t = 0; t < 4; ++t) {
        const int ra = wm * 64 + t * 16 + lrow;
        const int rbr = wn * 64 + t * 16 + lrow;
        af[t] = *(const bf16x8*)(AsB + ra * 128 + (sw ^ (ra & 7)) * 16);
        bfr[t] = *(const bf16x8*)(BsB + rbr * 128 + (sw ^ (rbr & 7)) * 16);
      }
#pragma unroll
      for (int ti = 0; ti < 4; ++ti)
#pragma unroll
        for (int tj = 0; tj < 4; ++tj)
          acc[ti][tj] =
              __builtin_amdgcn_mfma_f32_16x16x32_bf16(af[ti], bfr[tj], acc[ti][tj], 0, 0, 0);
    }
  }

  // ---- epilogue: 4 chunks of 32 rows; LDS transpose then nt-vector stream
#pragma unroll
  for (int ti = 0; ti < 4; ++ti) {
    __syncthreads();
#pragma unroll
    for (int tj = 0; tj < 4; ++tj)
#pragma unroll
      for (int r2 = 0; r2 < 4; ++r2)
        EP[(wm * 16 + lq * 4 + r2) * 132 + wn * 64 + tj * 16 + lrow] = acc[ti][tj][r2];
    __syncthreads();

    const int rr2 = tid >> 3;        // 0..31
    const int c0 = (tid & 7) * 4;    // first float4 col, stride 32 over k2i
    const int bl = (rr2 >> 4) * 64 + ti * 16 + (rr2 & 15);
    const int gr = bm0 + bl;
    float hr[16], hp4[4];
#pragma unroll
    for (int q = 0; q < 16; ++q) hr[q] = HR[bl * 17 + q];
#pragma unroll
    for (int q = 0; q < 4; ++q) hp4[q] = HP[bl * 5 + q];
    const float cm0 = 0.25f * (hr[0] + hr[4] + hr[8] + hr[12]);
    const float cm1 = 0.25f * (hr[1] + hr[5] + hr[9] + hr[13]);
    const float cm2 = 0.25f * (hr[2] + hr[6] + hr[10] + hr[14]);
    const float cm3 = 0.25f * (hr[3] + hr[7] + hr[11] + hr[15]);
    const float hps = 0.25f * (hp4[0] + hp4[1] + hp4[2] + hp4[3]);
    const float* xb = xs + (size_t)gr * SD + bn0;
    float* um = outMean + (size_t)gr * 1024 + bn0;
    float* uu = outUpd + (size_t)gr * 4096 + bn0;
#pragma unroll
    for (int k2i = 0; k2i < 4; ++k2i) {
      const int col = c0 + k2i * 32;
      f32x4 ov = *(const f32x4*)(EP + rr2 * 132 + col);
      ov += *(const f32x4*)(blayer + bn0 + col);
      const f32x4 x0 = *(const f32x4*)(xb + col);
      const f32x4 x1 = *(const f32x4*)(xb + 1024 + col);
      const f32x4 x2 = *(const f32x4*)(xb + 2048 + col);
      const f32x4 x3 = *(const f32x4*)(xb + 3072 + col);
      __builtin_nontemporal_store(cm0 * x0 + cm1 * x1 + cm2 * x2 + cm3 * x3 + ov * hps,
                                  (f32x4*)(um + col));
      __builtin_nontemporal_store(hr[0] * x0 + hr[1] * x1 + hr[2] * x2 + hr[3] * x3 + ov * hp4[0],
                                  (f32x4*)(uu + col));
      __builtin_nontemporal_store(hr[4] * x0 + hr[5] * x1 + hr[6] * x2 + hr[7] * x3 + ov * hp4[1],
                                  (f32x4*)(uu + 1024 + col));
      __builtin_nontemporal_store(hr[8] * x0 + hr[9] * x1 + hr[10] * x2 + hr[11] * x3 + ov * hp4[2],
                                  (f32x4*)(uu + 2048 + col));
      __builtin_nontemporal_store(hr[12] * x0 + hr[13] * x1 + hr[14] * x2 + hr[15] * x3 + ov * hp4[3],
                                  (f32x4*)(uu + 3072 + col));
    }
  }
}

// ---------------- launch ----------------
extern "C" void kernel_launch(void* const* d_in, const int* in_sizes, int n_in,
                              void* d_out, int out_size, void* d_ws, size_t ws_size,
                              hipStream_t stream) {
  const float* xs = (const float*)d_in[1];
  const float* Wpre = (const float*)d_in[2];
  const float* bpre = (const float*)d_in[3];
  const float* Wpost = (const float*)d_in[4];
  const float* bpost = (const float*)d_in[5];
  const float* Wres = (const float*)d_in[6];
  const float* bres = (const float*)d_in[7];
  const float* apre = (const float*)d_in[8];
  const float* apost = (const float*)d_in[9];
  const float* ares = (const float*)d_in[10];
  const float* gamma = (const float*)d_in[11];
  const float* beta = (const float*)d_in[12];
  const float* Wlayer = (const float*)d_in[13];
  const float* blayer = (const float*)d_in[14];

  const size_t OFF_LNAGG = (size_t)2 << 20;                     // 16 MB
  const size_t OFF_HRES = (size_t)18 << 20;                     // 512 KB
  const size_t OFF_HPOST = OFF_HRES + (size_t)BROWS * 16 * 4;   // 128 KB
  const size_t OFF_WSUM = OFF_HPOST + (size_t)BROWS * 4 * 4;    // 512 B
  const size_t OFF_WALL = OFF_WSUM + 512;                       // 384 KB
  const size_t NEED = OFF_WALL + (size_t)24 * SD * 4;
  if (ws_size < NEED) return;  // workspace too small — fail visibly

  char* ws = (char*)d_ws;
  unsigned short* wl16 = (unsigned short*)ws;
  unsigned short* lnagg = (unsigned short*)(ws + OFF_LNAGG);
  float* hresb = (float*)(ws + OFF_HRES);
  float* hpostb = (float*)(ws + OFF_HPOST);
  float* wsum = (float*)(ws + OFF_WSUM);
  float* Wall = (float*)(ws + OFF_WALL);

  float* outMean = (float*)d_out;
  float* outUpd = outMean + (size_t)BROWS * D;

  hipLaunchKernelGGL(k0_prep, dim3(1048), dim3(256), 0, stream, Wlayer, Wpre, Wpost, Wres,
                     wl16, Wall, wsum);
  hipLaunchKernelGGL(k1_rowpass, dim3(1024), dim3(512), 0, stream, xs, Wall, bpre, bpost,
                     bres, apre, apost, ares, gamma, beta, wsum, lnagg, hresb, hpostb);
  hipLaunchKernelGGL(k2_gemm_ep, dim3(64, 8), dim3(256), 0, stream, lnagg, wl16, blayer, xs,
                     hresb, hpostb, outMean, outUpd);
}

// Round 5
// 413.226 us; speedup vs baseline: 1.9228x; 1.0030x over previous
//
#include <hip/hip_runtime.h>

#define DEV __device__ __forceinline__

typedef __bf16 bf16x8 __attribute__((ext_vector_type(8)));
typedef float f32x4 __attribute__((ext_vector_type(4)));
typedef unsigned int u32;

constexpr int BROWS = 8192;
constexpr int D = 1024;
constexpr int SD = 4096;

// ---------------- helpers ----------------
DEV unsigned short f2bf(float f) {  // RNE float->bf16
  unsigned int u = __float_as_uint(f);
  u = (u + 0x7FFFu + ((u >> 16) & 1u)) >> 16;
  return (unsigned short)u;
}

DEV float wred(float v) {  // full 64-lane butterfly sum (result in all lanes)
#pragma unroll
  for (int m = 1; m < 64; m <<= 1) v += __shfl_xor(v, m);
  return v;
}

DEV float sigmoidf(float x) { return 1.0f / (1.0f + __expf(-x)); }

DEV void async_ld16(const void* g, void* l) {  // 16B global -> LDS DMA
  __builtin_amdgcn_global_load_lds((const __attribute__((address_space(1))) u32*)g,
                                   (__attribute__((address_space(3))) u32*)l, 16, 0, 0);
}

// ---------------- K0: prep — W_layer->bf16, pack 24 gate rows, row-sums ----
__global__ __launch_bounds__(256) void k0_prep(
    const float* __restrict__ Wlayer, const float* __restrict__ Wpre,
    const float* __restrict__ Wpost, const float* __restrict__ Wres,
    unsigned short* __restrict__ wl16, float* __restrict__ Wall,
    float* __restrict__ wsum) {
  const int bx = blockIdx.x, tid = threadIdx.x;
  if (bx < 1024) {  // W_layer fp32 -> bf16
    const int i = bx * 1024 + tid * 4;
    float4 v = *(const float4*)(Wlayer + i);
    ushort4 u = make_ushort4(f2bf(v.x), f2bf(v.y), f2bf(v.z), f2bf(v.w));
    *(ushort4*)(wl16 + i) = u;
  } else {  // pack gate row j into Wall + row-sum
    const int j = bx - 1024;  // 0..23
    const float* src = (j < 4) ? (Wpre + j * SD)
                               : (j < 8 ? (Wpost + (j - 4) * SD) : (Wres + (j - 8) * SD));
    float s = 0.f;
    for (int i = tid * 4; i < SD; i += 1024) {
      float4 v = *(const float4*)(src + i);
      *(float4*)(Wall + j * SD + i) = v;
      s += v.x + v.y + v.z + v.w;
    }
    s = wred(s);
    __shared__ float tmp[4];
    if ((tid & 63) == 0) tmp[tid >> 6] = s;
    __syncthreads();
    if (tid == 0) wsum[j] = tmp[0] + tmp[1] + tmp[2] + tmp[3];
  }
}

// ---------------- K1: fused per-row pass, LDS-staged pipelined ----------------
// Block = 8 rows, 8 waves (512 thr). x DMA'd (global_load_lds) into an 8-slot
// LDS ring (64 KB); ALL waves read x from LDS. Wave w: dots j in [3w,3w+3)
// for all 8 rows (acc[3][8]) + stats for row w (folded into r==wv).
// Pipeline (round-4 fix): DMA issued 3 steps ahead; W refill issued AFTER
// CMP so in FIFO order W(i) precedes D(i+2)/D(i+3) -> the compiler's W-reg
// wait (vmcnt(5)) retires nothing newer; D(i+2),D(i+3) stay in flight across
// the barrier. Slack: W = 2 steps (L2 ~250cy), DMA = 2-3 steps (>= HBM 900cy).
// Ring-8 removes WAR aliasing at depth 3 (write slot (i+3)&7 vs reads (i)&7,
// (i-1)&7: all distinct; wave skew bounded by the per-step barrier).
// FIFO-simulated explicit waits: step0 "9", steady "12" (non-binding; the
// compiler's vmcnt(5) is the pacer), peel "11"/"10"/"6".
// Register lessons kept: no min-waves launch_bounds arg (spill), runtime
// 2-step loop body (unroll blowup), waves_per_eu(2) allows growth past 128.
__global__ __launch_bounds__(512) __attribute__((amdgpu_waves_per_eu(2)))
void k1_rowpass(
    const float* __restrict__ xs, const float* __restrict__ Wall,
    const float* __restrict__ bpre, const float* __restrict__ bpost,
    const float* __restrict__ bres,
    const float* __restrict__ s_apre, const float* __restrict__ s_apost,
    const float* __restrict__ s_ares,
    const float* __restrict__ gamma, const float* __restrict__ beta,
    const float* __restrict__ wsum,
    unsigned short* __restrict__ lnagg,
    float* __restrict__ hres_g, float* __restrict__ hpost_g) {
  const int tid = threadIdx.x;
  const int wv = tid >> 6;   // 0..7
  const int ln = tid & 63;
  const int rb = blockIdx.x * 8;
  const int l4 = ln * 4;

  __shared__ float XR[8][8][256];  // 64 KB x ring: [slot][row][k-chunk]
  __shared__ float DOT[24][8];
  __shared__ float MU[8];
  __shared__ float RSH[8];
  __shared__ float HPRE[8][4];
  float* XR0 = &XR[0][0][0];

  const int jb = wv * 3;
  const float* Wb = Wall + (size_t)jb * SD;
  // DMA: wave w stages row w. Per-lane dest = slot base + tid*16B -> row
  // tid>>6 = wv, col (tid&63)*4 — matches global_load_lds's lane-linear
  // contract and the global source row.
  const float* gx = xs + (size_t)(rb + wv) * SD + l4;

  float acc[3][8];
#pragma unroll
  for (int q = 0; q < 3; ++q)
#pragma unroll
    for (int r = 0; r < 8; ++r) acc[q][r] = 0.f;
  float s2 = 0.f, q2 = 0.f;  // stats for row wv

  float4 wbufA[3], wbufB[3];

#define LDW(dst, it)                                                      \
  {                                                                       \
    const float* p_ = Wb + (it) * 256 + l4;                               \
    _Pragma("unroll") for (int q = 0; q < 3; ++q) dst[q] =                \
        *(const float4*)(p_ + (size_t)q * SD);                            \
  }
#define DMA1(it)                                                          \
  async_ld16(gx + (it) * 256, XR0 + ((it) & 7) * 2048 + tid * 4);
#define CMP(it, W)                                                        \
  {                                                                       \
    const int so_ = ((it) & 7) * 2048;                                    \
    _Pragma("unroll") for (int r = 0; r < 8; ++r) {                       \
      float4 xv_ = *(const float4*)(XR0 + so_ + r * 256 + l4);            \
      if (r == wv) { /* wave-uniform branch: stats for own row */         \
        s2 += xv_.x + xv_.y + xv_.z + xv_.w;                              \
        q2 += xv_.x * xv_.x + xv_.y * xv_.y + xv_.z * xv_.z +             \
              xv_.w * xv_.w;                                              \
      }                                                                   \
      _Pragma("unroll") for (int q = 0; q < 3; ++q) acc[q][r] +=          \
          W[q].x * xv_.x + W[q].y * xv_.y + W[q].z * xv_.z +              \
          W[q].w * xv_.w;                                                 \
    }                                                                     \
  }
#define WAITB(LIT)                                                        \
  asm volatile("s_waitcnt vmcnt(" LIT ") lgkmcnt(0)" ::: "memory");       \
  __builtin_amdgcn_s_barrier();                                           \
  asm volatile("" ::: "memory");

  // prologue: 3 DMAs + 2 W buffers in flight
  DMA1(0);
  DMA1(1);
  DMA1(2);
  asm volatile("" ::: "memory");
  LDW(wbufA, 0);
  LDW(wbufB, 1);

  // step 0
  DMA1(3);
  WAITB("9")
  CMP(0, wbufA);
  LDW(wbufA, 2);

#pragma unroll 1
  for (int it = 1; it <= 11; it += 2) {  // steps 1..12, runtime addresses
    DMA1(it + 3);
    WAITB("12")
    CMP(it, wbufB);
    LDW(wbufB, it + 2);
    DMA1(it + 4);
    WAITB("12")
    CMP(it + 1, wbufA);
    LDW(wbufA, it + 3);
  }
  // peeled: steps 13..15 (no more DMA)
  WAITB("11")
  CMP(13, wbufB);
  LDW(wbufB, 15);
  WAITB("10")
  CMP(14, wbufA);
  WAITB("6")
  CMP(15, wbufB);
#undef WAITB
#undef CMP
#undef DMA1
#undef LDW

  // ---- reductions (butterfly; result in all lanes) ----
#pragma unroll
  for (int q = 0; q < 3; ++q)
#pragma unroll
    for (int r = 0; r < 8; ++r) acc[q][r] = wred(acc[q][r]);
  s2 = wred(s2);
  q2 = wred(q2);

  if (ln == 0) {
#pragma unroll
    for (int q = 0; q < 3; ++q)
#pragma unroll
      for (int r = 0; r < 8; ++r) DOT[jb + q][r] = acc[q][r];
    const float mu = s2 * (1.0f / 4096.0f);
    MU[wv] = mu;
    RSH[wv] = rsqrtf(q2 * (1.0f / 4096.0f) - mu * mu + 1e-5f);
  }
  __syncthreads();

  // ---- gates ----
  if (wv < 2) {  // sinkhorn: wave w -> rows 4w..4w+3; 64 lanes = 4 rows x 16
    const float ares = s_ares[0];
    const int rr = (wv << 2) + (ln >> 4), jj = ln & 15;
    const float corr = RSH[rr] * (DOT[8 + jj][rr] - MU[rr] * wsum[8 + jj]);
    float M = __expf(ares * (corr + bres[jj]));
#pragma unroll 1
    for (int itr = 0; itr < 20; ++itr) {
      float rs_ = M + __shfl_xor(M, 1);
      rs_ += __shfl_xor(rs_, 2);
      M *= __builtin_amdgcn_rcpf(rs_ + 1e-8f);
      float cs = M + __shfl_xor(M, 4);
      cs += __shfl_xor(cs, 8);
      M *= __builtin_amdgcn_rcpf(cs + 1e-8f);
    }
    hres_g[(size_t)(rb + rr) * 16 + jj] = M;
  } else if (wv == 2) {
    if (ln < 32) {
      const int r = ln >> 2, s = ln & 3;
      const float corr = RSH[r] * (DOT[s][r] - MU[r] * wsum[s]);
      HPRE[r][s] = sigmoidf(s_apre[0] * (corr + bpre[s]));
    }
  } else if (wv == 3) {
    if (ln < 32) {
      const int r = ln >> 2, s = ln & 3;
      const float corr = RSH[r] * (DOT[4 + s][r] - MU[r] * wsum[4 + s]);
      hpost_g[(size_t)(rb + r) * 4 + s] = 2.0f * sigmoidf(s_apost[0] * (corr + bpost[s]));
    }
  }
  __syncthreads();

  // ---- phase 2: x_agg + LN + bf16 store — wave w owns row rb+w
  // (x re-read hits L2: block's 32 KB was just fetched)
  {
    const int b = rb + wv;
    const float* xb = xs + (size_t)b * SD;
    const float h0 = HPRE[wv][0], h1 = HPRE[wv][1], h2 = HPRE[wv][2], h3 = HPRE[wv][3];
    float4 agg[4];
    float asum = 0.f, asq = 0.f;
#pragma unroll
    for (int i2 = 0; i2 < 4; ++i2) {
      const int d = i2 * 256 + l4;
      float4 g0 = *(const float4*)(xb + d);
      float4 g1 = *(const float4*)(xb + D + d);
      float4 g2 = *(const float4*)(xb + 2 * D + d);
      float4 g3 = *(const float4*)(xb + 3 * D + d);
      float4 a;
      a.x = h0 * g0.x + h1 * g1.x + h2 * g2.x + h3 * g3.x;
      a.y = h0 * g0.y + h1 * g1.y + h2 * g2.y + h3 * g3.y;
      a.z = h0 * g0.z + h1 * g1.z + h2 * g2.z + h3 * g3.z;
      a.w = h0 * g0.w + h1 * g1.w + h2 * g2.w + h3 * g3.w;
      agg[i2] = a;
      asum += a.x + a.y + a.z + a.w;
      asq += a.x * a.x + a.y * a.y + a.z * a.z + a.w * a.w;
    }
    asum = wred(asum);
    asq = wred(asq);
    const float mu2 = asum * (1.0f / 1024.0f);
    const float rstd2 = rsqrtf(asq * (1.0f / 1024.0f) - mu2 * mu2 + 1e-5f);
#pragma unroll
    for (int i2 = 0; i2 < 4; ++i2) {
      const int d = i2 * 256 + l4;
      float4 g = *(const float4*)(gamma + d);
      float4 bb = *(const float4*)(beta + d);
      ushort4 u;
      u.x = f2bf((agg[i2].x - mu2) * rstd2 * g.x + bb.x);
      u.y = f2bf((agg[i2].y - mu2) * rstd2 * g.y + bb.y);
      u.z = f2bf((agg[i2].z - mu2) * rstd2 * g.z + bb.z);
      u.w = f2bf((agg[i2].w - mu2) * rstd2 * g.w + bb.w);
      *(ushort4*)(lnagg + (size_t)b * D + d) = u;
    }
  }
}

// ---------------- K2: bf16 MFMA GEMM + fused epilogue ----------------
__global__ __launch_bounds__(256) void k2_gemm_ep(
    const unsigned short* __restrict__ A,   // lnagg bf16 [8192][1024]
    const unsigned short* __restrict__ Bw,  // W_layer bf16 [1024][1024]
    const float* __restrict__ blayer,
    const float* __restrict__ xs,
    const float* __restrict__ hres_g, const float* __restrict__ hpost_g,
    float* __restrict__ outMean, float* __restrict__ outUpd) {
  __shared__ char smem[44032];
  char* AsB = smem;            // 16384 B: 128 rows x 64 bf16 (8 chunks of 16B)
  char* BsB = smem + 16384;    // 16384 B
  float* EP = (float*)smem;    // epilogue overlay: 32 x 132 fp32 = 16896 B
  float* HR = (float*)(smem + 32768);  // 128 x 17
  float* HP = (float*)(smem + 41472);  // 128 x 5

  const int tid = threadIdx.x;
  const int l = tid & 63;
  const int wv = tid >> 6;
  const int wm = wv >> 1, wn = wv & 1;
  const int lrow = l & 15, lq = l >> 4;
  const int bm0 = blockIdx.x * 128;
  const int bn0 = blockIdx.y * 128;

#pragma unroll
  for (int i = 0; i < 8; ++i) {
    int idx = i * 256 + tid;  // 0..2047
    HR[(idx >> 4) * 17 + (idx & 15)] = hres_g[(size_t)bm0 * 16 + idx];
  }
#pragma unroll
  for (int i = 0; i < 2; ++i) {
    int idx = i * 256 + tid;  // 0..511
    HP[(idx >> 2) * 5 + (idx & 3)] = hpost_g[(size_t)bm0 * 4 + idx];
  }

  f32x4 acc[4][4] = {};

#pragma unroll 1
  for (int kt = 0; kt < 16; ++kt) {
    __syncthreads();
#pragma unroll
    for (int c = 0; c < 4; ++c) {
      const int idx = c * 256 + tid;              // 16B-chunk index 0..1023
      const int row = idx >> 3, cc = idx & 7;
      const int gch = cc ^ (row & 7);             // XOR swizzle on global side
      async_ld16((const char*)A + ((size_t)(bm0 + row) << 11) + kt * 128 + gch * 16,
                 AsB + idx * 16);
      async_ld16((const char*)Bw + ((size_t)(bn0 + row) << 11) + kt * 128 + gch * 16,
                 BsB + idx * 16);
    }
    __syncthreads();
#pragma unroll
    for (int kk = 0; kk < 2; ++kk) {
      bf16x8 af[4], bfr[4];
      const int sw = (kk * 4 + lq);
#pragma unroll
      for (int t = 0; t < 4; ++t) {
        const int ra = wm * 64 + t * 16 + lrow;
        const int rbr = wn * 64 + t * 16 + lrow;
        af[t] = *(const bf16x8*)(AsB + ra * 128 + (sw ^ (ra & 7)) * 16);
        bfr[t] = *(const bf16x8*)(BsB + rbr * 128 + (sw ^ (rbr & 7)) * 16);
      }
#pragma unroll
      for (int ti = 0; ti < 4; ++ti)
#pragma unroll
        for (int tj = 0; tj < 4; ++tj)
          acc[ti][tj] =
              __builtin_amdgcn_mfma_f32_16x16x32_bf16(af[ti], bfr[tj], acc[ti][tj], 0, 0, 0);
    }
  }

  // ---- epilogue: 4 chunks of 32 rows; LDS transpose then nt-vector stream
#pragma unroll
  for (int ti = 0; ti < 4; ++ti) {
    __syncthreads();
#pragma unroll
    for (int tj = 0; tj < 4; ++tj)
#pragma unroll
      for (int r2 = 0; r2 < 4; ++r2)
        EP[(wm * 16 + lq * 4 + r2) * 132 + wn * 64 + tj * 16 + lrow] = acc[ti][tj][r2];
    __syncthreads();

    const int rr2 = tid >> 3;        // 0..31
    const int c0 = (tid & 7) * 4;    // first float4 col, stride 32 over k2i
    const int bl = (rr2 >> 4) * 64 + ti * 16 + (rr2 & 15);
    const int gr = bm0 + bl;
    float hr[16], hp4[4];
#pragma unroll
    for (int q = 0; q < 16; ++q) hr[q] = HR[bl * 17 + q];
#pragma unroll
    for (int q = 0; q < 4; ++q) hp4[q] = HP[bl * 5 + q];
    const float cm0 = 0.25f * (hr[0] + hr[4] + hr[8] + hr[12]);
    const float cm1 = 0.25f * (hr[1] + hr[5] + hr[9] + hr[13]);
    const float cm2 = 0.25f * (hr[2] + hr[6] + hr[10] + hr[14]);
    const float cm3 = 0.25f * (hr[3] + hr[7] + hr[11] + hr[15]);
    const float hps = 0.25f * (hp4[0] + hp4[1] + hp4[2] + hp4[3]);
    const float* xb = xs + (size_t)gr * SD + bn0;
    float* um = outMean + (size_t)gr * 1024 + bn0;
    float* uu = outUpd + (size_t)gr * 4096 + bn0;
#pragma unroll
    for (int k2i = 0; k2i < 4; ++k2i) {
      const int col = c0 + k2i * 32;
      f32x4 ov = *(const f32x4*)(EP + rr2 * 132 + col);
      ov += *(const f32x4*)(blayer + bn0 + col);
      const f32x4 x0 = *(const f32x4*)(xb + col);
      const f32x4 x1 = *(const f32x4*)(xb + 1024 + col);
      const f32x4 x2 = *(const f32x4*)(xb + 2048 + col);
      const f32x4 x3 = *(const f32x4*)(xb + 3072 + col);
      __builtin_nontemporal_store(cm0 * x0 + cm1 * x1 + cm2 * x2 + cm3 * x3 + ov * hps,
                                  (f32x4*)(um + col));
      __builtin_nontemporal_store(hr[0] * x0 + hr[1] * x1 + hr[2] * x2 + hr[3] * x3 + ov * hp4[0],
                                  (f32x4*)(uu + col));
      __builtin_nontemporal_store(hr[4] * x0 + hr[5] * x1 + hr[6] * x2 + hr[7] * x3 + ov * hp4[1],
                                  (f32x4*)(uu + 1024 + col));
      __builtin_nontemporal_store(hr[8] * x0 + hr[9] * x1 + hr[10] * x2 + hr[11] * x3 + ov * hp4[2],
                                  (f32x4*)(uu + 2048 + col));
      __builtin_nontemporal_store(hr[12] * x0 + hr[13] * x1 + hr[14] * x2 + hr[15] * x3 + ov * hp4[3],
                                  (f32x4*)(uu + 3072 + col));
    }
  }
}

// ---------------- launch ----------------
extern "C" void kernel_launch(void* const* d_in, const int* in_sizes, int n_in,
                              void* d_out, int out_size, void* d_ws, size_t ws_size,
                              hipStream_t stream) {
  const float* xs = (const float*)d_in[1];
  const float* Wpre = (const float*)d_in[2];
  const float* bpre = (const float*)d_in[3];
  const float* Wpost = (const float*)d_in[4];
  const float* bpost = (const float*)d_in[5];
  const float* Wres = (const float*)d_in[6];
  const float* bres = (const float*)d_in[7];
  const float* apre = (const float*)d_in[8];
  const float* apost = (const float*)d_in[9];
  const float* ares = (const float*)d_in[10];
  const float* gamma = (const float*)d_in[11];
  const float* beta = (const float*)d_in[12];
  const float* Wlayer = (const float*)d_in[13];
  const float* blayer = (const float*)d_in[14];

  const size_t OFF_LNAGG = (size_t)2 << 20;                     // 16 MB
  const size_t OFF_HRES = (size_t)18 << 20;                     // 512 KB
  const size_t OFF_HPOST = OFF_HRES + (size_t)BROWS * 16 * 4;   // 128 KB
  const size_t OFF_WSUM = OFF_HPOST + (size_t)BROWS * 4 * 4;    // 512 B
  const size_t OFF_WALL = OFF_WSUM + 512;                       // 384 KB
  const size_t NEED = OFF_WALL + (size_t)24 * SD * 4;
  if (ws_size < NEED) return;  // workspace too small — fail visibly

  char* ws = (char*)d_ws;
  unsigned short* wl16 = (unsigned short*)ws;
  unsigned short* lnagg = (unsigned short*)(ws + OFF_LNAGG);
  float* hresb = (float*)(ws + OFF_HRES);
  float* hpostb = (float*)(ws + OFF_HPOST);
  float* wsum = (float*)(ws + OFF_WSUM);
  float* Wall = (float*)(ws + OFF_WALL);

  float* outMean = (float*)d_out;
  float* outUpd = outMean + (size_t)BROWS * D;

  hipLaunchKernelGGL(k0_prep, dim3(1048), dim3(256), 0, stream, Wlayer, Wpre, Wpost, Wres,
                     wl16, Wall, wsum);
  hipLaunchKernelGGL(k1_rowpass, dim3(1024), dim3(512), 0, stream, xs, Wall, bpre, bpost,
                     bres, apre, apost, ares, gamma, beta, wsum, lnagg, hresb, hpostb);
  hipLaunchKernelGGL(k2_gemm_ep, dim3(64, 8), dim3(256), 0, stream, lnagg, wl16, blayer, xs,
                     hresb, hpostb, outMean, outUpd);
}